// Round 9
// baseline (228.781 us; speedup 1.0000x reference)
//
#include <hip/hip_runtime.h>
#include <hip/hip_bf16.h>

#define B_    8
#define N_    2048
#define FIN_  128
#define FOUT_ 64
#define ALPHA_ 0.2f
#define LN_EPS_ 1e-5f
#define LOG2E_ 1.4426950408889634f

typedef __attribute__((ext_vector_type(8))) short short8;
typedef __attribute__((ext_vector_type(4))) float f32x4;

__device__ __forceinline__ short2 pk_bf(float a, float b) {   // packed RNE f32x2 -> bf16x2
    __hip_bfloat162 h = __float22bfloat162_rn(float2{a, b});
    return *reinterpret_cast<short2*>(&h);
}

// ============ kernel 1: h = x@W (bf16 MFMA) -> h_T bf16; s1,s2 (PRE-SCALED by log2e) ============
// 512 blocks x 256 thr; block = 32 rows; wave: M-tile mt=wave&1, N-tiles {nt0,nt0+1}.
__global__ __launch_bounds__(256) void k_proj(
    const float* __restrict__ x,    // (B*N, 128)
    const float* __restrict__ W,    // (128, 64)  L2-resident
    const float* __restrict__ a,    // (128,)
    unsigned short* __restrict__ hT,// (B*64, 2048) bf16 bits: h_T[b][o][j]
    float* __restrict__ s1, float* __restrict__ s2)   // prescaled by log2e
{
    __shared__ short Wb[16 * 64 * 8];     // 16 KB: W B-frags, set u = ks*4+nt
    __shared__ float Wa1l[FIN_], Wa2l[FIN_];
    const int t = threadIdx.x;
    const int row0 = blockIdx.x * 32;
    const int b   = row0 >> 11;
    const int ib0 = row0 & (N_ - 1);

    #pragma unroll
    for (int c = 0; c < 4; ++c) {
        int g = t + 256 * c;
        int u = g >> 6, ln = g & 63;
        int ks = u >> 2, nt = u & 3;
        int n  = nt * 16 + (ln & 15);
        int k0 = ks * 32 + (ln >> 4) * 8;
        short8 v;
        #pragma unroll
        for (int jj = 0; jj < 8; jj += 2) {
            short2 p = pk_bf(W[(k0 + jj) * FOUT_ + n], W[(k0 + jj + 1) * FOUT_ + n]);
            v[jj] = p.x; v[jj + 1] = p.y;
        }
        *(short8*)&Wb[g * 8] = v;
    }
    if (t < FIN_) {
        float a1 = 0.f, a2 = 0.f;
        #pragma unroll
        for (int n = 0; n < FOUT_; n += 4) {
            float4 wv  = *(const float4*)&W[t * FOUT_ + n];
            float4 av1 = *(const float4*)&a[n];
            float4 av2 = *(const float4*)&a[FOUT_ + n];
            a1 += wv.x * av1.x + wv.y * av1.y + wv.z * av1.z + wv.w * av1.w;
            a2 += wv.x * av2.x + wv.y * av2.y + wv.z * av2.z + wv.w * av2.w;
        }
        Wa1l[t] = a1 * LOG2E_; Wa2l[t] = a2 * LOG2E_;   // prescale -> s1,s2 in log2 domain
    }
    __syncthreads();

    const int wave = t >> 6, lane = t & 63;
    const int m = lane & 15, quad = lane >> 4;
    const int mt = wave & 1, nt0 = (wave >> 1) * 2;
    const int row = row0 + mt * 16 + m;

    short8 fa[4];
    float s1p = 0.f, s2p = 0.f;
    #pragma unroll
    for (int ks = 0; ks < 4; ++ks) {
        int k0 = ks * 32 + quad * 8;
        float4 x0 = *(const float4*)&x[(size_t)row * FIN_ + k0];
        float4 x1 = *(const float4*)&x[(size_t)row * FIN_ + k0 + 4];
        float xs[8] = {x0.x, x0.y, x0.z, x0.w, x1.x, x1.y, x1.z, x1.w};
        short8 v;
        #pragma unroll
        for (int jj = 0; jj < 8; jj += 2) {
            short2 p = pk_bf(xs[jj], xs[jj + 1]);
            v[jj] = p.x; v[jj + 1] = p.y;
        }
        #pragma unroll
        for (int jj = 0; jj < 8; ++jj) {
            s1p += xs[jj] * Wa1l[k0 + jj];
            s2p += xs[jj] * Wa2l[k0 + jj];
        }
        fa[ks] = v;
    }
    s1p += __shfl_xor(s1p, 16); s1p += __shfl_xor(s1p, 32);
    s2p += __shfl_xor(s2p, 16); s2p += __shfl_xor(s2p, 32);
    if (wave < 2 && lane < 16) {
        s1[row0 + wave * 16 + lane] = s1p;
        s2[row0 + wave * 16 + lane] = s2p;
    }

    f32x4 acc[2];
    acc[0] = (f32x4){0.f, 0.f, 0.f, 0.f};
    acc[1] = (f32x4){0.f, 0.f, 0.f, 0.f};
    #pragma unroll
    for (int ks = 0; ks < 4; ++ks) {
        #pragma unroll
        for (int q = 0; q < 2; ++q) {
            short8 fb = *(short8*)&Wb[((ks * 4 + nt0 + q) * 64 + lane) * 8];
            acc[q] = __builtin_amdgcn_mfma_f32_16x16x32_bf16(fa[ks], fb, acc[q], 0, 0, 0);
        }
    }
    #pragma unroll
    for (int q = 0; q < 2; ++q) {
        int o  = (nt0 + q) * 16 + m;
        int ib = ib0 + mt * 16 + quad * 4;
        short2 p0 = pk_bf(acc[q][0], acc[q][1]);
        short2 p1 = pk_bf(acc[q][2], acc[q][3]);
        ushort4 hv;
        hv.x = (unsigned short)p0.x; hv.y = (unsigned short)p0.y;
        hv.z = (unsigned short)p1.x; hv.w = (unsigned short)p1.y;
        *(ushort4*)&hT[(size_t)(b * 64 + o) * N_ + ib] = hv;
    }
}

// ============ kernel 2: attention, barrier-free split-K, 2 j-tiles per iteration ============
// grid = B*(N/16) = 1024 blocks x 256 thr. Wave w owns j-slice ks=w; per iteration it
// processes j-tiles j0 and j0+128 (two independent chains -> 2x ILP). exp2-domain scores
// (s1,s2 prescaled), packed bf16 cvt, float4 s2l reads, l summed in f32 (LN absorbs it).
__global__ __launch_bounds__(256) void k_attn(
    const int* __restrict__ adj,
    const unsigned short* __restrict__ hT,
    const float* __restrict__ s1g, const float* __restrict__ s2g,
    const float* __restrict__ gamma, const float* __restrict__ beta,
    float* __restrict__ out)
{
    __shared__ float s2l[N_];              // 8 KB
    __shared__ float accL[4][16][64];      // 16 KB split-K partials
    __shared__ float lpw[4][16];
    __shared__ float red[4];

    const int t = threadIdx.x;
    const int wave = t >> 6, lane = t & 63;
    const int i_ = lane & 15, quad = lane >> 4;
    const int b  = blockIdx.x >> 7;
    const int i0 = (blockIdx.x & 127) * 16;
    const size_t sbase = (size_t)b * N_;
    const size_t hTb   = (size_t)b * 64 * N_;

    float4 v0 = *(const float4*)&s2g[sbase + 4 * t];
    float4 v1 = *(const float4*)&s2g[sbase + 4 * (t + 256)];
    *(float4*)&s2l[4 * t] = v0;
    *(float4*)&s2l[4 * (t + 256)] = v1;
    float mx = fmaxf(fmaxf(fmaxf(v0.x, v0.y), fmaxf(v0.z, v0.w)),
                     fmaxf(fmaxf(v1.x, v1.y), fmaxf(v1.z, v1.w)));
    #pragma unroll
    for (int d = 32; d; d >>= 1) mx = fmaxf(mx, __shfl_xor(mx, d));
    if (lane == 0) red[wave] = mx;
    __syncthreads();
    const float smax = fmaxf(fmaxf(red[0], red[1]), fmaxf(red[2], red[3]));
    const float s1v  = s1g[sbase + i0 + i_];
    const float mv   = fmaxf(s1v + smax, ALPHA_ * (s1v + smax));

    const int jr = wave * 32 + quad * 8;
    const int* adjrow = &adj[(sbase + i0 + i_) * N_ + jr];

    // prefetch adj for iteration 0 (tiles j=0 and j=128)
    int4 pa0 = *(const int4*)&adjrow[0];
    int4 pa1 = *(const int4*)&adjrow[4];
    int4 pb0 = *(const int4*)&adjrow[128];
    int4 pb1 = *(const int4*)&adjrow[132];

    f32x4 acc[4];
    #pragma unroll
    for (int nt = 0; nt < 4; ++nt) acc[nt] = (f32x4){0.f, 0.f, 0.f, 0.f};
    float lpart = 0.f;

    #pragma unroll 2
    for (int it = 0; it < 8; ++it) {
        const int j0 = it * 256;
        int am0[8] = {pa0.x, pa0.y, pa0.z, pa0.w, pa1.x, pa1.y, pa1.z, pa1.w};
        int am1[8] = {pb0.x, pb0.y, pb0.z, pb0.w, pb1.x, pb1.y, pb1.z, pb1.w};
        {   // prefetch next iteration's adj (wraps; harmless)
            int jn = ((it + 1) & 7) * 256;
            pa0 = *(const int4*)&adjrow[jn];
            pa1 = *(const int4*)&adjrow[jn + 4];
            pb0 = *(const int4*)&adjrow[jn + 128];
            pb1 = *(const int4*)&adjrow[jn + 132];
        }

        // ---- tile 0: j0 ----
        short8 hv0[4];
        #pragma unroll
        for (int nt = 0; nt < 4; ++nt)
            hv0[nt] = *(const short8*)&hT[hTb + (size_t)(nt * 16 + i_) * N_ + j0 + jr];
        short8 wv0;
        {
            float4 sa = *(const float4*)&s2l[j0 + jr];
            float4 sb = *(const float4*)&s2l[j0 + jr + 4];
            float sv[8] = {sa.x, sa.y, sa.z, sa.w, sb.x, sb.y, sb.z, sb.w};
            float w[8];
            #pragma unroll
            for (int jj = 0; jj < 8; ++jj) {
                float ev = s1v + sv[jj];
                ev = fmaxf(ev, ALPHA_ * ev);
                float e = exp2f(ev - mv);
                w[jj] = (am0[jj] > 0) ? e : 0.f;
                lpart += w[jj];
            }
            #pragma unroll
            for (int jj = 0; jj < 8; jj += 2) {
                short2 p = pk_bf(w[jj], w[jj + 1]);
                wv0[jj] = p.x; wv0[jj + 1] = p.y;
            }
        }

        // ---- tile 1: j0+128 (independent chain; hv1 loads overlap tile-0 MFMA) ----
        short8 hv1[4];
        #pragma unroll
        for (int nt = 0; nt < 4; ++nt)
            hv1[nt] = *(const short8*)&hT[hTb + (size_t)(nt * 16 + i_) * N_ + j0 + 128 + jr];

        #pragma unroll
        for (int nt = 0; nt < 4; ++nt)
            acc[nt] = __builtin_amdgcn_mfma_f32_16x16x32_bf16(wv0, hv0[nt], acc[nt], 0, 0, 0);

        short8 wv1;
        {
            float4 sa = *(const float4*)&s2l[j0 + 128 + jr];
            float4 sb = *(const float4*)&s2l[j0 + 128 + jr + 4];
            float sv[8] = {sa.x, sa.y, sa.z, sa.w, sb.x, sb.y, sb.z, sb.w};
            float w[8];
            #pragma unroll
            for (int jj = 0; jj < 8; ++jj) {
                float ev = s1v + sv[jj];
                ev = fmaxf(ev, ALPHA_ * ev);
                float e = exp2f(ev - mv);
                w[jj] = (am1[jj] > 0) ? e : 0.f;
                lpart += w[jj];
            }
            #pragma unroll
            for (int jj = 0; jj < 8; jj += 2) {
                short2 p = pk_bf(w[jj], w[jj + 1]);
                wv1[jj] = p.x; wv1[jj + 1] = p.y;
            }
        }
        #pragma unroll
        for (int nt = 0; nt < 4; ++nt)
            acc[nt] = __builtin_amdgcn_mfma_f32_16x16x32_bf16(wv1, hv1[nt], acc[nt], 0, 0, 0);
    }

    lpart += __shfl_xor(lpart, 16);
    lpart += __shfl_xor(lpart, 32);
    if (lane < 16) lpw[wave][lane] = lpart;

    #pragma unroll
    for (int nt = 0; nt < 4; ++nt)
        #pragma unroll
        for (int reg = 0; reg < 4; ++reg)
            accL[wave][nt * 4 + reg][lane] = acc[nt][reg];
    __syncthreads();

    {
        const int o = lane, ntc = o >> 4, oc = o & 15;
        const float g  = gamma[o];
        const float be = beta[o];
        #pragma unroll
        for (int rr = 0; rr < 4; ++rr) {
            int i = wave * 4 + rr;
            int s = ntc * 4 + (i & 3), lp = (i >> 2) * 16 + oc;
            float c = accL[0][s][lp] + accL[1][s][lp] + accL[2][s][lp] + accL[3][s][lp];
            float l = lpw[0][i] + lpw[1][i] + lpw[2][i] + lpw[3][i];
            float v = c / l;
            float mu = v;
            #pragma unroll
            for (int d = 32; d; d >>= 1) mu += __shfl_xor(mu, d);
            mu *= (1.f / 64.f);
            float dv = v - mu;
            float var = dv * dv;
            #pragma unroll
            for (int d = 32; d; d >>= 1) var += __shfl_xor(var, d);
            var *= (1.f / 64.f);
            float y = dv * rsqrtf(var + LN_EPS_) * g + be;
            out[(sbase + i0 + i) * FOUT_ + o] = y > 0.f ? y : __expf(y) - 1.f;
        }
    }
}

extern "C" void kernel_launch(void* const* d_in, const int* in_sizes, int n_in,
                              void* d_out, int out_size, void* d_ws, size_t ws_size,
                              hipStream_t stream) {
    const float* x     = (const float*)d_in[0];
    const int*   adj   = (const int*)d_in[1];
    const float* W     = (const float*)d_in[2];
    const float* a     = (const float*)d_in[3];
    const float* gamma = (const float*)d_in[4];
    const float* beta  = (const float*)d_in[5];
    float* out = (float*)d_out;

    char* ws = (char*)d_ws;
    unsigned short* hT = (unsigned short*)ws;                      // 2 MB
    float* s1 = (float*)(ws + (size_t)B_ * 64 * N_ * 2);           // 64 KB
    float* s2 = s1 + (size_t)B_ * N_;                              // 64 KB

    k_proj<<<512, 256, 0, stream>>>(x, W, a, hT, s1, s2);
    k_attn<<<B_ * (N_ / 16), 256, 0, stream>>>(adj, hT, s1, s2, gamma, beta, out);
}